// Round 1
// baseline (98.599 us; speedup 1.0000x reference)
//
#include <hip/hip_runtime.h>

// Problem constants (fixed by the reference): B=64, IDF=128, CDF=256, L=256, S2=1024.
// Pipeline (restructured, sourceC never materialized):
//   M    = wc @ W          [8192 x 256]   split-bf16 (3-term)
//   logit= M @ ctx         [128 x 256]/b  split-bf16 (3-term), fused softmax -> attn + out2
//   Yt   = attn @ ctx^T'   [128 x 256]/b  plain bf16   (Yt[i,c] = sum_l attn[i,l] ctx[c,l])
//   out1 = Yt @ W^T'       [128 x 1024]/b plain bf16   (out1[i,s] = sum_c Yt[i,c] W[s,c])
// Workspace use: ~77.1 MB.

typedef unsigned short u16;
typedef __attribute__((ext_vector_type(8))) short bf16x8;   // 8 bf16 = 4 VGPRs
typedef __attribute__((ext_vector_type(4))) float f32x4;    // MFMA accumulator
typedef __attribute__((ext_vector_type(4))) unsigned int u32x4; // 16B copies

#define MFMA_BF16(a, b, c) __builtin_amdgcn_mfma_f32_16x16x32_bf16((a), (b), (c), 0, 0, 0)

__device__ __forceinline__ u16 f2bf(float v) {
    unsigned int u = __float_as_uint(v);
    u += 0x7fffu + ((u >> 16) & 1u);          // RNE (finite data only)
    return (u16)(u >> 16);
}
__device__ __forceinline__ float bf2f(u16 h) {
    return __uint_as_float(((unsigned int)h) << 16);
}
__device__ __forceinline__ void split2(float v, u16& h, u16& l) {
    h = f2bf(v);
    l = f2bf(v - bf2f(h));                    // residual exact in f32 (Sterbenz)
}

// ---------------------------------------------------------------------------
// Elementwise split f32 -> (hi, lo) bf16. n4 = number of float4 groups.
__global__ void k_split(const float* __restrict__ x, u16* __restrict__ hi,
                        u16* __restrict__ lo, int n4) {
    int i = blockIdx.x * blockDim.x + threadIdx.x;
    int stride = gridDim.x * blockDim.x;
    for (; i < n4; i += stride) {
        float4 v = ((const float4*)x)[i];
        u16 h0, l0, h1, l1, h2, l2, h3, l3;
        split2(v.x, h0, l0); split2(v.y, h1, l1);
        split2(v.z, h2, l2); split2(v.w, h3, l3);
        u32x4 hv, lv;
        hv.x = (unsigned)h0 | ((unsigned)h1 << 16);
        hv.y = (unsigned)h2 | ((unsigned)h3 << 16);
        lv.x = (unsigned)l0 | ((unsigned)l1 << 16);
        lv.y = (unsigned)l2 | ((unsigned)l3 << 16);
        // store 4 bf16 = 8B each
        *(uint2*)(hi + (size_t)i * 4) = make_uint2(hv.x, hv.y);
        *(uint2*)(lo + (size_t)i * 4) = make_uint2(lv.x, lv.y);
    }
}

// ---------------------------------------------------------------------------
// Per-matrix: write plain_h = bf16(src) [R][C], and transposed split
// t_h/t_l [C][R]. grid = (C/32, R/32, nmat); block = 256.
__global__ void k_tsplit(const float* __restrict__ src, u16* __restrict__ plain_h,
                         u16* __restrict__ t_h, u16* __restrict__ t_l,
                         int R, int C) {
    __shared__ float tile[32][33];
    const int b = blockIdx.z;
    const float* s = src + (size_t)b * R * C;
    const int c0 = blockIdx.x * 32, r0 = blockIdx.y * 32;
    const int tx = threadIdx.x & 31, ty0 = threadIdx.x >> 5;   // 32 x 8
#pragma unroll
    for (int i = 0; i < 4; i++) {
        int ty = ty0 + i * 8;
        float v = s[(size_t)(r0 + ty) * C + c0 + tx];
        tile[ty][tx] = v;
        plain_h[(size_t)b * R * C + (size_t)(r0 + ty) * C + c0 + tx] = f2bf(v);
    }
    __syncthreads();
#pragma unroll
    for (int i = 0; i < 4; i++) {
        int ty = ty0 + i * 8;
        float v = tile[tx][ty];            // src[r0+tx][c0+ty]
        u16 h, l; split2(v, h, l);
        size_t o = (size_t)b * R * C + (size_t)(c0 + ty) * R + r0 + tx;
        t_h[o] = h;
        t_l[o] = l;
    }
}

// ---------------------------------------------------------------------------
// Generic tiled MFMA GEMM:  D[m][n] = sum_k A[m][k] * BT[n][k]
// A: [M][K] bf16 (hi, + lo if SPLIT); BT: [N][K] bf16 (hi, + lo if SPLIT).
// Tile 64x64, BK=32, 256 threads = 4 waves in 2x2, each wave 32x32 (2x2 frags).
// EPI: 0 = f32 out, 1 = bf16 out (hi), 2 = bf16 split out (hi+lo).
template<bool SPLIT, int EPI>
__global__ __launch_bounds__(256) void k_gemm(
    const u16* __restrict__ Ah, const u16* __restrict__ Al,
    const u16* __restrict__ Bh, const u16* __restrict__ Bl,
    u16* __restrict__ outH, u16* __restrict__ outL, float* __restrict__ outF,
    int M, int N, int K,
    long long sA, long long sB, long long sO)
{
    __shared__ u16 AsH[64][40];
    __shared__ u16 BsH[64][40];
    __shared__ u16 AsL[SPLIT ? 64 : 1][40];
    __shared__ u16 BsL[SPLIT ? 64 : 1][40];

    const int b  = blockIdx.z;
    const int m0 = blockIdx.y * 64;
    const int n0 = blockIdx.x * 64;
    const u16* A_h = Ah + (size_t)b * sA;
    const u16* B_h = Bh + (size_t)b * sB;
    const u16* A_l = SPLIT ? (Al + (size_t)b * sA) : nullptr;
    const u16* B_l = SPLIT ? (Bl + (size_t)b * sB) : nullptr;

    const int t = threadIdx.x;
    const int lane = t & 63, wid = t >> 6;
    const int g = lane >> 4, r = lane & 15;
    const int mB = (wid >> 1) * 32, nB = (wid & 1) * 32;
    const int srow = t >> 2, scol = (t & 3) * 8;

    f32x4 acc[2][2] = {};

    for (int k0 = 0; k0 < K; k0 += 32) {
        size_t ga = (size_t)(m0 + srow) * K + k0 + scol;
        size_t gb = (size_t)(n0 + srow) * K + k0 + scol;
        *(u32x4*)&AsH[srow][scol] = *(const u32x4*)(A_h + ga);
        *(u32x4*)&BsH[srow][scol] = *(const u32x4*)(B_h + gb);
        if constexpr (SPLIT) {
            *(u32x4*)&AsL[srow][scol] = *(const u32x4*)(A_l + ga);
            *(u32x4*)&BsL[srow][scol] = *(const u32x4*)(B_l + gb);
        }
        __syncthreads();

        bf16x8 aH[2], bH[2], aL[2], bL[2];
#pragma unroll
        for (int mi = 0; mi < 2; mi++) {
            aH[mi] = *(const bf16x8*)&AsH[mB + 16 * mi + r][g * 8];
            if constexpr (SPLIT) aL[mi] = *(const bf16x8*)&AsL[mB + 16 * mi + r][g * 8];
        }
#pragma unroll
        for (int ni = 0; ni < 2; ni++) {
            bH[ni] = *(const bf16x8*)&BsH[nB + 16 * ni + r][g * 8];
            if constexpr (SPLIT) bL[ni] = *(const bf16x8*)&BsL[nB + 16 * ni + r][g * 8];
        }
#pragma unroll
        for (int mi = 0; mi < 2; mi++)
#pragma unroll
            for (int ni = 0; ni < 2; ni++) {
                acc[mi][ni] = MFMA_BF16(aH[mi], bH[ni], acc[mi][ni]);
                if constexpr (SPLIT) {
                    acc[mi][ni] = MFMA_BF16(aH[mi], bL[ni], acc[mi][ni]);
                    acc[mi][ni] = MFMA_BF16(aL[mi], bH[ni], acc[mi][ni]);
                }
            }
        __syncthreads();
    }

#pragma unroll
    for (int mi = 0; mi < 2; mi++)
#pragma unroll
        for (int ni = 0; ni < 2; ni++)
#pragma unroll
            for (int rr = 0; rr < 4; rr++) {
                int row = m0 + mB + 16 * mi + 4 * g + rr;   // C/D: row = 4*(lane>>4)+reg
                int col = n0 + nB + 16 * ni + r;            //      col = lane&15
                float v = acc[mi][ni][rr];
                size_t o = (size_t)b * sO + (size_t)row * N + col;
                if constexpr (EPI == 0) {
                    outF[o] = v;
                } else if constexpr (EPI == 1) {
                    outH[o] = f2bf(v);
                } else {
                    u16 h, l; split2(v, h, l);
                    outH[o] = h; outL[o] = l;
                }
            }
}

// ---------------------------------------------------------------------------
// logits = M @ ctx (split-bf16, via ctxT as BT), fused softmax over L=256.
// Writes attn (bf16, [B*128][256] row-major) and out2 = attn^T (f32 [B][256][128]).
// grid = (1, 2, B); block = 256 (4 waves x 16 rows, full 256-wide N per wave).
__global__ __launch_bounds__(256) void k_logits_softmax(
    const u16* __restrict__ Mh, const u16* __restrict__ Ml,
    const u16* __restrict__ CtH, const u16* __restrict__ CtL,
    u16* __restrict__ attnH, float* __restrict__ out2)
{
    __shared__ u16 AsH[64][40], AsL[64][40];
    __shared__ u16 BsH[256][40], BsL[256][40];
    const int b = blockIdx.z;
    const int m0 = blockIdx.y * 64;            // 0 or 64 within the batch's 128 rows
    const int t = threadIdx.x;
    const int lane = t & 63, wid = t >> 6;
    const int g = lane >> 4, r = lane & 15;

    f32x4 acc[16] = {};

    const int srow = t >> 2, scol = (t & 3) * 8;
    for (int k0 = 0; k0 < 256; k0 += 32) {
        size_t ga = (size_t)(b * 128 + m0 + srow) * 256 + k0 + scol;
        *(u32x4*)&AsH[srow][scol] = *(const u32x4*)(Mh + ga);
        *(u32x4*)&AsL[srow][scol] = *(const u32x4*)(Ml + ga);
#pragma unroll
        for (int j = 0; j < 4; j++) {
            int idx = t + j * 256;
            int br = idx >> 2, bc = (idx & 3) * 8;
            size_t gb = (size_t)b * 65536 + (size_t)br * 256 + k0 + bc;
            *(u32x4*)&BsH[br][bc] = *(const u32x4*)(CtH + gb);
            *(u32x4*)&BsL[br][bc] = *(const u32x4*)(CtL + gb);
        }
        __syncthreads();

        bf16x8 aH = *(const bf16x8*)&AsH[16 * wid + r][g * 8];
        bf16x8 aL = *(const bf16x8*)&AsL[16 * wid + r][g * 8];
#pragma unroll
        for (int ni = 0; ni < 16; ni++) {
            bf16x8 bH = *(const bf16x8*)&BsH[16 * ni + r][g * 8];
            bf16x8 bL = *(const bf16x8*)&BsL[16 * ni + r][g * 8];
            acc[ni] = MFMA_BF16(aH, bH, acc[ni]);
            acc[ni] = MFMA_BF16(aH, bL, acc[ni]);
            acc[ni] = MFMA_BF16(aL, bH, acc[ni]);
        }
        __syncthreads();
    }

    // softmax per output row; rows held by this lane: m0 + 16*wid + 4*g + rr
#pragma unroll
    for (int rr = 0; rr < 4; rr++) {
        float mx = -3.0e38f;
#pragma unroll
        for (int ni = 0; ni < 16; ni++) mx = fmaxf(mx, acc[ni][rr]);
#pragma unroll
        for (int m = 1; m < 16; m <<= 1) mx = fmaxf(mx, __shfl_xor(mx, m));
        float s = 0.f;
#pragma unroll
        for (int ni = 0; ni < 16; ni++) {
            float e = __expf(acc[ni][rr] - mx);
            acc[ni][rr] = e;
            s += e;
        }
#pragma unroll
        for (int m = 1; m < 16; m <<= 1) s += __shfl_xor(s, m);
        float inv = 1.f / s;

        const int i_loc = m0 + 16 * wid + 4 * g + rr;          // 0..127
        const size_t arow = (size_t)(b * 128 + i_loc) * 256;
        const size_t obase = (size_t)b * 32768;                // 256*128
#pragma unroll
        for (int ni = 0; ni < 16; ni++) {
            float v = acc[ni][rr] * inv;
            int col = 16 * ni + r;
            attnH[arow + col] = f2bf(v);                       // attn [i][l], coalesced
            out2[obase + (size_t)col * 128 + i_loc] = v;       // attn^T [l][i], scattered
        }
    }
}

// ---------------------------------------------------------------------------
extern "C" void kernel_launch(void* const* d_in, const int* in_sizes, int n_in,
                              void* d_out, int out_size, void* d_ws, size_t ws_size,
                              hipStream_t stream) {
    const int B = 64, IDF = 128, CDF = 256, L = 256, S2 = 1024;
    const float* wc  = (const float*)d_in[0];   // [B, IDF, S2]
    const float* ctx = (const float*)d_in[1];   // [B, CDF, L]
    const float* W   = (const float*)d_in[2];   // [S2, CDF]
    float* out1 = (float*)d_out;                          // [B,IDF,S2] = 8388608
    float* out2 = (float*)d_out + (size_t)B * IDF * S2;   // [B,L,IDF] = 2097152

    char* ws = (char*)d_ws;
    size_t off = 0;
    auto alloc = [&](size_t bytes) -> char* {
        char* p = ws + off;
        off += (bytes + 255) & ~(size_t)255;
        return p;
    };
    u16* WtH   = (u16*)alloc((size_t)CDF * S2 * 2);        // W^T hi   [256][1024]
    u16* WtL   = (u16*)alloc((size_t)CDF * S2 * 2);        // W^T lo
    u16* Wp    = (u16*)alloc((size_t)S2 * CDF * 2);        // W hi     [1024][256]
    u16* ctxTH = (u16*)alloc((size_t)B * L * CDF * 2);     // ctx^T hi [B][l][c]
    u16* ctxTL = (u16*)alloc((size_t)B * L * CDF * 2);     // ctx^T lo
    u16* ctxP  = (u16*)alloc((size_t)B * CDF * L * 2);     // ctx hi   [B][c][l]
    u16* wcH   = (u16*)alloc((size_t)B * IDF * S2 * 2);    // wc hi    [8192][1024]
    u16* wcL   = (u16*)alloc((size_t)B * IDF * S2 * 2);    // wc lo
    u16* MH    = (u16*)alloc((size_t)B * IDF * CDF * 2);   // M hi     [8192][256]
    u16* ML    = (u16*)alloc((size_t)B * IDF * CDF * 2);   // M lo
    u16* attnH = (u16*)alloc((size_t)B * IDF * L * 2);     // attn hi  [8192][256]
    u16* YtH   = (u16*)alloc((size_t)B * IDF * CDF * 2);   // Yt hi    [8192][256]
    (void)ws_size; // requires ~77.1 MB of workspace

    // converts
    k_split<<<2048, 256, 0, stream>>>(wc, wcH, wcL, (B * IDF * S2) / 4);
    k_tsplit<<<dim3(CDF / 32, S2 / 32, 1), 256, 0, stream>>>(W, Wp, WtH, WtL, S2, CDF);
    k_tsplit<<<dim3(L / 32, CDF / 32, B), 256, 0, stream>>>(ctx, ctxP, ctxTH, ctxTL, CDF, L);

    // G1: M = wc @ W   (A=[8192,1024], BT=W^T [256,1024]) split, out bf16 hi/lo
    k_gemm<true, 2><<<dim3(CDF / 64, (B * IDF) / 64, 1), 256, 0, stream>>>(
        wcH, wcL, WtH, WtL, MH, ML, nullptr,
        B * IDF, CDF, S2, 0, 0, 0);

    // G2: logits = M @ ctx + softmax -> attn bf16 + out2 f32
    k_logits_softmax<<<dim3(1, 2, B), 256, 0, stream>>>(MH, ML, ctxTH, ctxTL, attnH, out2);

    // G3: Yt = attn @ ctx^T'  (A=attn [128,256]/b, BT=ctx [256,256]/b) plain, out bf16
    k_gemm<false, 1><<<dim3(CDF / 64, IDF / 64, B), 256, 0, stream>>>(
        attnH, nullptr, ctxP, nullptr, YtH, nullptr, nullptr,
        IDF, CDF, L, (long long)IDF * L, (long long)CDF * L, (long long)IDF * CDF);

    // G4: out1 = Yt @ W^T'   (A=Yt [128,256]/b, BT=W [1024,256] shared) plain, out f32
    k_gemm<false, 0><<<dim3(S2 / 64, IDF / 64, B), 256, 0, stream>>>(
        YtH, nullptr, Wp, nullptr, nullptr, nullptr, out1,
        IDF, S2, CDF, (long long)IDF * CDF, 0, (long long)IDF * S2);
}

// Round 3
// 82.506 us; speedup vs baseline: 1.1951x; 1.1951x over previous
//
#include <hip/hip_runtime.h>

// B=64, IDF=128, CDF=256, L=256, S2=1024.
// Pipeline (sourceC never materialized; all converts fused into GEMM staging):
//   tsplitW  : W  -> W^T hi/lo                      (0.5+0.5 MB)
//   tsplitC  : ctx-> ctx^T hi/lo                    (8.4+8.4 MB)
//   G1: M    = wc(f32,split-on-fly) @ W^T(hi/lo)    [8192x256], 3-term split, out hi/lo
//   G2: logit= M(hi/lo) @ ctx^T(hi/lo) + softmax    -> attn bf16 + out2 f32
//   G3: Yt   = attn(bf16) @ ctx(f32->bf16)          [128x256]/b, out bf16
//   G4: out1 = Yt(bf16) @ W(f32->bf16)              [128x1024]/b, out f32

typedef unsigned short u16;
typedef __attribute__((ext_vector_type(8))) short bf16x8;       // 8 bf16 = 4 VGPRs
typedef __attribute__((ext_vector_type(4))) float f32x4;        // MFMA accumulator
typedef __attribute__((ext_vector_type(4))) unsigned int u32x4; // 16B chunk

#define MFMA_BF16(a, b, c) __builtin_amdgcn_mfma_f32_16x16x32_bf16((a), (b), (c), 0, 0, 0)

__device__ __forceinline__ u16 f2bf(float v) {
    unsigned u = __float_as_uint(v);
    u += 0x7fffu + ((u >> 16) & 1u);          // RNE (finite data only)
    return (u16)(u >> 16);
}
__device__ __forceinline__ float bf2f(u16 h) {
    return __uint_as_float(((unsigned)h) << 16);
}
__device__ __forceinline__ void split2(float v, u16& h, u16& l) {
    h = f2bf(v);
    l = f2bf(v - bf2f(h));                    // residual exact in f32
}
// pack two floats' split halves: .x = hi pair, .y = lo pair
__device__ __forceinline__ uint2 splitpack(float a, float b) {
    u16 ha, la, hb, lb; split2(a, ha, la); split2(b, hb, lb);
    return make_uint2((unsigned)ha | ((unsigned)hb << 16),
                      (unsigned)la | ((unsigned)lb << 16));
}
__device__ __forceinline__ unsigned pack2h(float a, float b) {
    return (unsigned)f2bf(a) | ((unsigned)f2bf(b) << 16);
}
// XCD-chunked bijective block swizzle (grid size divisible by 8)
__device__ __forceinline__ int xcd_swz(int bid, int nwg) {
    return (bid & 7) * (nwg >> 3) + (bid >> 3);
}

// ---------------------------------------------------------------------------
// Transpose + split: src [nmat][R][C] f32 -> t_h/t_l [nmat][C][R] bf16.
__global__ void k_tsplit(const float* __restrict__ src, u16* __restrict__ t_h,
                         u16* __restrict__ t_l, int R, int C) {
    __shared__ float tile[32][33];
    const int b = blockIdx.z;
    const float* s = src + (size_t)b * R * C;
    const int c0 = blockIdx.x * 32, r0 = blockIdx.y * 32;
    const int tx = threadIdx.x & 31, ty0 = threadIdx.x >> 5;   // 32 x 8
#pragma unroll
    for (int i = 0; i < 4; i++) {
        int ty = ty0 + i * 8;
        tile[ty][tx] = s[(size_t)(r0 + ty) * C + c0 + tx];
    }
    __syncthreads();
#pragma unroll
    for (int i = 0; i < 4; i++) {
        int ty = ty0 + i * 8;
        float v = tile[tx][ty];            // src[r0+tx][c0+ty]
        u16 h, l; split2(v, h, l);
        size_t o = (size_t)b * R * C + (size_t)(c0 + ty) * R + r0 + tx;
        t_h[o] = h; t_l[o] = l;
    }
}

// ---------------------------------------------------------------------------
// Generic tiled MFMA GEMM:  D[m][n] = sum_k A[m][k] * BT[n][k]
// SPLIT: A = f32 (split on the fly, 3-term), BT = pre-split bf16 hi/lo.
// !SPLIT: A = bf16, BT = f32 (converted hi-only on the fly).
// Tile 64x64, BK=64, 256 thr = 4 waves (2x2 of 32x32). Double-buffered LDS,
// one barrier/iter; loads for tile t+1 issued before tile t's MFMAs (T14).
// LDS layout XOR-swizzled: 16B-group cg stored at cg ^ (row&7)  (T2).
// EPI: 0 = f32 out, 1 = bf16 out, 2 = bf16 hi/lo out.
template<bool SPLIT, int EPI>
__global__ __launch_bounds__(256, 2) void k_gemm2(
    const float* __restrict__ Af, const u16* __restrict__ Ab,
    const u16* __restrict__ Bh, const u16* __restrict__ Bl,
    const float* __restrict__ Bf,
    u16* __restrict__ outH, u16* __restrict__ outL, float* __restrict__ outF,
    int NBX, int NBY, int N, int K,
    long long sA, long long sB, long long sO)
{
    __shared__ __align__(16) u16 AsH[2][64 * 64];
    __shared__ __align__(16) u16 BsH[2][64 * 64];
    __shared__ __align__(16) u16 AsL[SPLIT ? 2 : 1][SPLIT ? 64 * 64 : 8];
    __shared__ __align__(16) u16 BsL[SPLIT ? 2 : 1][SPLIT ? 64 * 64 : 8];

    const int sbl = xcd_swz((int)blockIdx.x, (int)gridDim.x);
    const int bx = sbl % NBX;
    const int by = (sbl / NBX) % NBY;
    const int bz = sbl / (NBX * NBY);
    const int m0 = by * 64, n0 = bx * 64;

    const float* Afb = SPLIT ? (Af + (size_t)bz * sA) : nullptr;
    const u16*   Abb = SPLIT ? nullptr : (Ab + (size_t)bz * sA);
    const u16*   Bhb = SPLIT ? (Bh + (size_t)bz * sB) : nullptr;
    const u16*   Blb = SPLIT ? (Bl + (size_t)bz * sB) : nullptr;
    const float* Bfb = SPLIT ? nullptr : (Bf + (size_t)bz * sB);

    const int t = threadIdx.x;
    const int lane = t & 63, wid = t >> 6;
    const int g = lane >> 4, r = lane & 15;
    const int mB = (wid >> 1) * 32, nB = (wid & 1) * 32;

    // staging geometry: thread covers row srow, 16 elems at col sc4*16
    const int srow = t >> 2, sc4 = t & 3;
    const int wg0 = ((sc4 << 1) | 0) ^ (srow & 7);
    const int wg1 = ((sc4 << 1) | 1) ^ (srow & 7);
    const int wo0 = srow * 64 + wg0 * 8;   // u16 index of swizzled 16B slot
    const int wo1 = srow * 64 + wg1 * 8;

    float4 af0, af1, af2, af3;     // SPLIT: A f32
    u32x4 vbh0, vbh1, vbl0, vbl1;  // SPLIT: B hi/lo
    u32x4 ab0, ab1;                // !SPLIT: A bf16
    float4 bg0, bg1, bg2, bg3;     // !SPLIT: B f32

    auto LOAD = [&](int k0) {
        if constexpr (SPLIT) {
            const float4* ap = (const float4*)(Afb + (size_t)(m0 + srow) * K + k0 + sc4 * 16);
            af0 = ap[0]; af1 = ap[1]; af2 = ap[2]; af3 = ap[3];
            const u32x4* bph = (const u32x4*)(Bhb + (size_t)(n0 + srow) * K + k0 + sc4 * 16);
            vbh0 = bph[0]; vbh1 = bph[1];
            const u32x4* bpl = (const u32x4*)(Blb + (size_t)(n0 + srow) * K + k0 + sc4 * 16);
            vbl0 = bpl[0]; vbl1 = bpl[1];
        } else {
            const u32x4* ap = (const u32x4*)(Abb + (size_t)(m0 + srow) * K + k0 + sc4 * 16);
            ab0 = ap[0]; ab1 = ap[1];
            const float4* bp = (const float4*)(Bfb + (size_t)(n0 + srow) * K + k0 + sc4 * 16);
            bg0 = bp[0]; bg1 = bp[1]; bg2 = bp[2]; bg3 = bp[3];
        }
    };

    auto STORE = [&](int bi) {
        if constexpr (SPLIT) {
            u32x4 h0, h1, l0, l1;
            uint2 p;
            p = splitpack(af0.x, af0.y); h0.x = p.x; l0.x = p.y;
            p = splitpack(af0.z, af0.w); h0.y = p.x; l0.y = p.y;
            p = splitpack(af1.x, af1.y); h0.z = p.x; l0.z = p.y;
            p = splitpack(af1.z, af1.w); h0.w = p.x; l0.w = p.y;
            p = splitpack(af2.x, af2.y); h1.x = p.x; l1.x = p.y;
            p = splitpack(af2.z, af2.w); h1.y = p.x; l1.y = p.y;
            p = splitpack(af3.x, af3.y); h1.z = p.x; l1.z = p.y;
            p = splitpack(af3.z, af3.w); h1.w = p.x; l1.w = p.y;
            *(u32x4*)&AsH[bi][wo0] = h0;   *(u32x4*)&AsH[bi][wo1] = h1;
            *(u32x4*)&AsL[bi][wo0] = l0;   *(u32x4*)&AsL[bi][wo1] = l1;
            *(u32x4*)&BsH[bi][wo0] = vbh0; *(u32x4*)&BsH[bi][wo1] = vbh1;
            *(u32x4*)&BsL[bi][wo0] = vbl0; *(u32x4*)&BsL[bi][wo1] = vbl1;
        } else {
            *(u32x4*)&AsH[bi][wo0] = ab0;  *(u32x4*)&AsH[bi][wo1] = ab1;
            u32x4 h0, h1;
            h0.x = pack2h(bg0.x, bg0.y); h0.y = pack2h(bg0.z, bg0.w);
            h0.z = pack2h(bg1.x, bg1.y); h0.w = pack2h(bg1.z, bg1.w);
            h1.x = pack2h(bg2.x, bg2.y); h1.y = pack2h(bg2.z, bg2.w);
            h1.z = pack2h(bg3.x, bg3.y); h1.w = pack2h(bg3.z, bg3.w);
            *(u32x4*)&BsH[bi][wo0] = h0;   *(u32x4*)&BsH[bi][wo1] = h1;
        }
    };

    f32x4 acc[2][2] = {};
    int cur = 0;
    LOAD(0);
    STORE(0);
    __syncthreads();

    const int nt = K >> 6;
    for (int tt = 0; tt < nt; ++tt) {
        if (tt + 1 < nt) LOAD((tt + 1) << 6);

        bf16x8 aH[2][2], bH[2][2], aL[2][2], bL[2][2];
#pragma unroll
        for (int mi = 0; mi < 2; mi++) {
            const int rowA = mB + 16 * mi + r;
            const int sw = rowA & 7;
#pragma unroll
            for (int kh = 0; kh < 2; kh++) {
                const int off = rowA * 64 + (((kh << 2) | g) ^ sw) * 8;
                aH[mi][kh] = *(const bf16x8*)&AsH[cur][off];
                if constexpr (SPLIT) aL[mi][kh] = *(const bf16x8*)&AsL[cur][off];
            }
        }
#pragma unroll
        for (int ni = 0; ni < 2; ni++) {
            const int rowB = nB + 16 * ni + r;
            const int sw = rowB & 7;
#pragma unroll
            for (int kh = 0; kh < 2; kh++) {
                const int off = rowB * 64 + (((kh << 2) | g) ^ sw) * 8;
                bH[ni][kh] = *(const bf16x8*)&BsH[cur][off];
                if constexpr (SPLIT) bL[ni][kh] = *(const bf16x8*)&BsL[cur][off];
            }
        }
#pragma unroll
        for (int mi = 0; mi < 2; mi++)
#pragma unroll
            for (int ni = 0; ni < 2; ni++)
#pragma unroll
                for (int kh = 0; kh < 2; kh++) {
                    acc[mi][ni] = MFMA_BF16(aH[mi][kh], bH[ni][kh], acc[mi][ni]);
                    if constexpr (SPLIT) {
                        acc[mi][ni] = MFMA_BF16(aH[mi][kh], bL[ni][kh], acc[mi][ni]);
                        acc[mi][ni] = MFMA_BF16(aL[mi][kh], bH[ni][kh], acc[mi][ni]);
                    }
                }

        if (tt + 1 < nt) STORE(cur ^ 1);
        __syncthreads();
        cur ^= 1;
    }

#pragma unroll
    for (int mi = 0; mi < 2; mi++)
#pragma unroll
        for (int ni = 0; ni < 2; ni++)
#pragma unroll
            for (int rr = 0; rr < 4; rr++) {
                const int row = m0 + mB + 16 * mi + 4 * g + rr;  // C/D: row=4*(lane>>4)+reg
                const int col = n0 + nB + 16 * ni + r;           //      col=lane&15
                const float v = acc[mi][ni][rr];
                const size_t o = (size_t)bz * sO + (size_t)row * N + col;
                if constexpr (EPI == 0) outF[o] = v;
                else if constexpr (EPI == 1) outH[o] = f2bf(v);
                else { u16 h, l; split2(v, h, l); outH[o] = h; outL[o] = l; }
            }
}

// ---------------------------------------------------------------------------
// logits = M @ ctx (split, via ctxT), fused softmax over L=256.
// 256 blocks x 128 thr; each block = 32 rows (2 waves x 16), full N=256.
__global__ __launch_bounds__(128) void k_logits_softmax(
    const u16* __restrict__ Mh, const u16* __restrict__ Ml,
    const u16* __restrict__ CtH, const u16* __restrict__ CtL,
    u16* __restrict__ attnH, float* __restrict__ out2)
{
    __shared__ u16 AsH[32][40], AsL[32][40];
    __shared__ u16 BsH[256][40], BsL[256][40];
    const int sbl = xcd_swz((int)blockIdx.x, (int)gridDim.x);
    const int b = sbl >> 2;
    const int m0 = (sbl & 3) * 32;
    const int t = threadIdx.x;
    const int lane = t & 63, wid = t >> 6;
    const int g = lane >> 4, r = lane & 15;

    f32x4 acc[16] = {};
    const int srow = t >> 2, scol = (t & 3) * 8;

    for (int k0 = 0; k0 < 256; k0 += 32) {
        size_t ga = (size_t)(b * 128 + m0 + srow) * 256 + k0 + scol;
        *(u32x4*)&AsH[srow][scol] = *(const u32x4*)(Mh + ga);
        *(u32x4*)&AsL[srow][scol] = *(const u32x4*)(Ml + ga);
#pragma unroll
        for (int j = 0; j < 8; j++) {
            int idx = t + j * 128;
            int br = idx >> 2, bc = (idx & 3) * 8;
            size_t gb = (size_t)b * 65536 + (size_t)br * 256 + k0 + bc;
            *(u32x4*)&BsH[br][bc] = *(const u32x4*)(CtH + gb);
            *(u32x4*)&BsL[br][bc] = *(const u32x4*)(CtL + gb);
        }
        __syncthreads();

        bf16x8 aH = *(const bf16x8*)&AsH[16 * wid + r][g * 8];
        bf16x8 aL = *(const bf16x8*)&AsL[16 * wid + r][g * 8];
#pragma unroll
        for (int ni = 0; ni < 16; ni++) {
            bf16x8 bH = *(const bf16x8*)&BsH[16 * ni + r][g * 8];
            bf16x8 bL = *(const bf16x8*)&BsL[16 * ni + r][g * 8];
            acc[ni] = MFMA_BF16(aH, bH, acc[ni]);
            acc[ni] = MFMA_BF16(aH, bL, acc[ni]);
            acc[ni] = MFMA_BF16(aL, bH, acc[ni]);
        }
        __syncthreads();
    }

#pragma unroll
    for (int rr = 0; rr < 4; rr++) {
        float mx = -3.0e38f;
#pragma unroll
        for (int ni = 0; ni < 16; ni++) mx = fmaxf(mx, acc[ni][rr]);
#pragma unroll
        for (int m = 1; m < 16; m <<= 1) mx = fmaxf(mx, __shfl_xor(mx, m));
        float s = 0.f;
#pragma unroll
        for (int ni = 0; ni < 16; ni++) {
            float e = __expf(acc[ni][rr] - mx);
            acc[ni][rr] = e;
            s += e;
        }
#pragma unroll
        for (int m = 1; m < 16; m <<= 1) s += __shfl_xor(s, m);
        float inv = 1.f / s;

        const int i_loc = m0 + 16 * wid + 4 * g + rr;          // 0..127
        const size_t arow = (size_t)(b * 128 + i_loc) * 256;
        const size_t obase = (size_t)b * 32768;                // 256*128
#pragma unroll
        for (int ni = 0; ni < 16; ni++) {
            float v = acc[ni][rr] * inv;
            int col = 16 * ni + r;
            attnH[arow + col] = f2bf(v);                       // attn [i][l]
            out2[obase + (size_t)col * 128 + i_loc] = v;       // attn^T [l][i]
        }
    }
}

// ---------------------------------------------------------------------------
extern "C" void kernel_launch(void* const* d_in, const int* in_sizes, int n_in,
                              void* d_out, int out_size, void* d_ws, size_t ws_size,
                              hipStream_t stream) {
    const int B = 64, IDF = 128, CDF = 256, L = 256, S2 = 1024;
    const float* wc  = (const float*)d_in[0];   // [B, IDF, S2] = [8192][1024]
    const float* ctx = (const float*)d_in[1];   // [B, CDF, L]
    const float* W   = (const float*)d_in[2];   // [S2, CDF]
    float* out1 = (float*)d_out;                          // [B,IDF,S2]
    float* out2 = (float*)d_out + (size_t)B * IDF * S2;   // [B,L,IDF]

    char* ws = (char*)d_ws;
    size_t off = 0;
    auto alloc = [&](size_t bytes) -> char* {
        char* p = ws + off;
        off += (bytes + 255) & ~(size_t)255;
        return p;
    };
    u16* WtH   = (u16*)alloc((size_t)CDF * S2 * 2);        // W^T hi [256][1024]
    u16* WtL   = (u16*)alloc((size_t)CDF * S2 * 2);
    u16* ctxTH = (u16*)alloc((size_t)B * L * CDF * 2);     // ctx^T hi [B][l][c]
    u16* ctxTL = (u16*)alloc((size_t)B * L * CDF * 2);
    u16* MH    = (u16*)alloc((size_t)B * IDF * CDF * 2);   // M hi [8192][256]
    u16* ML    = (u16*)alloc((size_t)B * IDF * CDF * 2);
    u16* attnH = (u16*)alloc((size_t)B * IDF * L * 2);     // attn [8192][256]
    u16* YtH   = (u16*)alloc((size_t)B * IDF * CDF * 2);   // Yt [B][128][256]
    (void)ws_size; // ~34.6 MB

    k_tsplit<<<dim3(CDF / 32, S2 / 32, 1), 256, 0, stream>>>(W, WtH, WtL, S2, CDF);
    k_tsplit<<<dim3(L / 32, CDF / 32, B), 256, 0, stream>>>(ctx, ctxTH, ctxTL, CDF, L);

    // G1: M = wc @ W   (A f32 split-on-fly, BT = W^T hi/lo), out hi/lo
    k_gemm2<true, 2><<<512, 256, 0, stream>>>(
        wc, nullptr, WtH, WtL, nullptr, MH, ML, nullptr,
        4, 128, 256, 1024, 0, 0, 0);

    // G2: logits + softmax -> attn bf16 + out2 f32
    k_logits_softmax<<<256, 128, 0, stream>>>(MH, ML, ctxTH, ctxTL, attnH, out2);

    // G3: Yt = attn @ ctx^T'  (A=attn bf16, BT = ctx f32->bf16), out bf16
    k_gemm2<false, 1><<<512, 256, 0, stream>>>(
        nullptr, attnH, nullptr, nullptr, ctx, YtH, nullptr, nullptr,
        4, 2, 256, 256, (long long)IDF * L, (long long)CDF * L, (long long)IDF * CDF);

    // G4: out1 = Yt @ W^T'  (A=Yt bf16, BT = W f32->bf16), out f32
    k_gemm2<false, 0><<<2048, 256, 0, stream>>>(
        nullptr, YtH, nullptr, nullptr, W, nullptr, nullptr, out1,
        16, 2, 1024, 256, (long long)IDF * CDF, 0, (long long)IDF * S2);
}

// Round 4
// 80.492 us; speedup vs baseline: 1.2250x; 1.0250x over previous
//
#include <hip/hip_runtime.h>

// B=64, IDF=128, CDF=256, L=256, S2=1024.
// Full-fp16 pipeline (no splits; converts fused into GEMM staging):
//   wcvt : W   -> W^T fp16 [256][1024]
//   tcvt : ctx -> ctx^T fp16 [B][L][C]
//   G1: M    = wc(f32->fp16 on-fly) @ W^T(fp16)   [8192x256]  out fp16
//   G2: logit= M(fp16) @ ctx^T(fp16) + softmax    -> attn fp16 + out2 f32
//   G3: Yt   = attn(fp16) @ ctx(f32->fp16 on-fly) [128x256]/b out fp16
//   G4: out1 = Yt(fp16) @ W(f32->fp16 on-fly)     [8192x1024] out f32

typedef unsigned short u16;
typedef _Float16 f16;
typedef __attribute__((ext_vector_type(8))) _Float16 f16x8;    // 4 VGPRs
typedef __attribute__((ext_vector_type(4))) float f32x4;       // MFMA acc
typedef __attribute__((ext_vector_type(4))) unsigned int u32x4;

#define MFMA_F16(a, b, c) __builtin_amdgcn_mfma_f32_16x16x32_f16((a), (b), (c), 0, 0, 0)

__device__ __forceinline__ u16 f2h(float v) {
    f16 h = (f16)v;                      // v_cvt_f16_f32, RNE
    return __builtin_bit_cast(u16, h);
}
__device__ __forceinline__ unsigned pk2h(float a, float b) {
    return (unsigned)f2h(a) | ((unsigned)f2h(b) << 16);
}
// XCD-chunked bijective block swizzle (grid size divisible by 8)
__device__ __forceinline__ int xcd_swz(int bid, int nwg) {
    return (bid & 7) * (nwg >> 3) + (bid >> 3);
}

// ---------------------------------------------------------------------------
// Transpose-convert: src [nmat][R][C] f32 -> dstT [nmat][C][R] fp16.
__global__ void k_tcvt(const float* __restrict__ src, u16* __restrict__ dstT,
                       int R, int C) {
    __shared__ float tile[32][33];
    const int b = blockIdx.z;
    const float* s = src + (size_t)b * R * C;
    const int c0 = blockIdx.x * 32, r0 = blockIdx.y * 32;
    const int tx = threadIdx.x & 31, ty0 = threadIdx.x >> 5;   // 32 x 8
#pragma unroll
    for (int i = 0; i < 4; i++) {
        int ty = ty0 + i * 8;
        tile[ty][tx] = s[(size_t)(r0 + ty) * C + c0 + tx];
    }
    __syncthreads();
#pragma unroll
    for (int i = 0; i < 4; i++) {
        int ty = ty0 + i * 8;
        dstT[(size_t)b * R * C + (size_t)(c0 + ty) * R + r0 + tx] = f2h(tile[tx][ty]);
    }
}

// ---------------------------------------------------------------------------
// Generic fp16 MFMA GEMM: D[m][n] = sum_k A[m][k] * BT[n][k]
// A/B sources are fp16 (u16) or f32 (converted during staging).
// Tile BM x BN, BK=64, 256 thr = 4 waves (2x2), wave tile (FM*16)x(FN*16).
// Double-buffered LDS, XOR-swizzled 16B groups (g ^ (row&7)). EPI: 0=f32, 1=fp16.
template<int BM, int BN, int FM, int FN, bool AF32, bool BF32, int EPI>
__global__ __launch_bounds__(256, 2) void k_gemm3(
    const float* __restrict__ Af, const u16* __restrict__ Ah,
    const float* __restrict__ Bf, const u16* __restrict__ Bh,
    u16* __restrict__ outH, float* __restrict__ outF,
    int NBX, int NBY, int N, int K,
    long long sA, long long sB, long long sO)
{
    static_assert(2 * FM * 16 == BM && 2 * FN * 16 == BN, "2x2 waves");
    __shared__ __align__(16) u16 As[2][BM * 64];
    __shared__ __align__(16) u16 Bs[2][BN * 64];

    const int sbl = xcd_swz((int)blockIdx.x, (int)gridDim.x);
    const int bx = sbl % NBX;
    const int by = (sbl / NBX) % NBY;
    const int bz = sbl / (NBX * NBY);
    const int m0 = by * BM, n0 = bx * BN;

    const int t = threadIdx.x;
    const int lane = t & 63, wid = t >> 6;
    const int g = lane >> 4, r = lane & 15;
    const int mB = (wid >> 1) * FM * 16, nB = (wid & 1) * FN * 16;

    constexpr int TPR_A = 256 / BM;      // threads per A row
    constexpr int NG_A  = 8 / TPR_A;     // 16B groups per thread
    const int arow = t / TPR_A;
    const int agb  = (t % TPR_A) * NG_A;
    constexpr int TPR_B = 256 / BN;
    constexpr int NG_B  = 8 / TPR_B;
    const int brow = t / TPR_B;
    const int bgb  = (t % TPR_B) * NG_B;

    const float* Afp = AF32 ? (Af + (size_t)bz * sA) : nullptr;
    const u16*   Ahp = AF32 ? nullptr : (Ah + (size_t)bz * sA);
    const float* Bfp = BF32 ? (Bf + (size_t)bz * sB) : nullptr;
    const u16*   Bhp = BF32 ? nullptr : (Bh + (size_t)bz * sB);

    float4 fa[AF32 ? NG_A * 2 : 1];
    u32x4  ua[AF32 ? 1 : NG_A];
    float4 fb[BF32 ? NG_B * 2 : 1];
    u32x4  ub[BF32 ? 1 : NG_B];

    auto LOAD = [&](int k0) {
        if constexpr (AF32) {
            const float4* p = (const float4*)(Afp + (size_t)(m0 + arow) * K + k0 + agb * 8);
#pragma unroll
            for (int i = 0; i < NG_A * 2; i++) fa[i] = p[i];
        } else {
            const u32x4* p = (const u32x4*)(Ahp + (size_t)(m0 + arow) * K + k0 + agb * 8);
#pragma unroll
            for (int i = 0; i < NG_A; i++) ua[i] = p[i];
        }
        if constexpr (BF32) {
            const float4* p = (const float4*)(Bfp + (size_t)(n0 + brow) * K + k0 + bgb * 8);
#pragma unroll
            for (int i = 0; i < NG_B * 2; i++) fb[i] = p[i];
        } else {
            const u32x4* p = (const u32x4*)(Bhp + (size_t)(n0 + brow) * K + k0 + bgb * 8);
#pragma unroll
            for (int i = 0; i < NG_B; i++) ub[i] = p[i];
        }
    };

    auto STORE = [&](int bi) {
#pragma unroll
        for (int i = 0; i < NG_A; i++) {
            u32x4 c;
            if constexpr (AF32) {
                c.x = pk2h(fa[2 * i].x, fa[2 * i].y);
                c.y = pk2h(fa[2 * i].z, fa[2 * i].w);
                c.z = pk2h(fa[2 * i + 1].x, fa[2 * i + 1].y);
                c.w = pk2h(fa[2 * i + 1].z, fa[2 * i + 1].w);
            } else {
                c = ua[i];
            }
            const int gw = (agb + i) ^ (arow & 7);
            *(u32x4*)&As[bi][arow * 64 + gw * 8] = c;
        }
#pragma unroll
        for (int i = 0; i < NG_B; i++) {
            u32x4 c;
            if constexpr (BF32) {
                c.x = pk2h(fb[2 * i].x, fb[2 * i].y);
                c.y = pk2h(fb[2 * i].z, fb[2 * i].w);
                c.z = pk2h(fb[2 * i + 1].x, fb[2 * i + 1].y);
                c.w = pk2h(fb[2 * i + 1].z, fb[2 * i + 1].w);
            } else {
                c = ub[i];
            }
            const int gw = (bgb + i) ^ (brow & 7);
            *(u32x4*)&Bs[bi][brow * 64 + gw * 8] = c;
        }
    };

    f32x4 acc[FM][FN] = {};
    int cur = 0;
    LOAD(0);
    STORE(0);
    __syncthreads();

    const int nt = K >> 6;
    for (int tt = 0; tt < nt; ++tt) {
        if (tt + 1 < nt) LOAD((tt + 1) << 6);

#pragma unroll
        for (int kh = 0; kh < 2; kh++) {
            f16x8 aF[FM], bF[FN];
#pragma unroll
            for (int mi = 0; mi < FM; mi++) {
                const int row = mB + 16 * mi + r;
                const int ga = ((kh << 2) | g) ^ (row & 7);
                aF[mi] = *(const f16x8*)&As[cur][row * 64 + ga * 8];
            }
#pragma unroll
            for (int ni = 0; ni < FN; ni++) {
                const int row = nB + 16 * ni + r;
                const int gb2 = ((kh << 2) | g) ^ (row & 7);
                bF[ni] = *(const f16x8*)&Bs[cur][row * 64 + gb2 * 8];
            }
#pragma unroll
            for (int mi = 0; mi < FM; mi++)
#pragma unroll
                for (int ni = 0; ni < FN; ni++)
                    acc[mi][ni] = MFMA_F16(aF[mi], bF[ni], acc[mi][ni]);
        }

        if (tt + 1 < nt) STORE(cur ^ 1);
        __syncthreads();
        cur ^= 1;
    }

#pragma unroll
    for (int mi = 0; mi < FM; mi++)
#pragma unroll
        for (int ni = 0; ni < FN; ni++)
#pragma unroll
            for (int rr = 0; rr < 4; rr++) {
                const int row = m0 + mB + 16 * mi + 4 * g + rr;  // C/D: row=4*(lane>>4)+reg
                const int col = n0 + nB + 16 * ni + r;           //      col=lane&15
                const float v = acc[mi][ni][rr];
                const size_t o = (size_t)bz * sO + (size_t)row * N + col;
                if constexpr (EPI == 0) outF[o] = v;
                else outH[o] = f2h(v);
            }
}

// ---------------------------------------------------------------------------
// logits = M @ ctx (fp16, via ctxT), fused softmax over L=256.
// 256 blocks x 128 thr; each block = 32 rows (2 waves x 16), full N=256.
__global__ __launch_bounds__(128) void k_logits_softmax(
    const u16* __restrict__ Mh, const u16* __restrict__ CtH,
    u16* __restrict__ attnH, float* __restrict__ out2)
{
    __shared__ u16 AsH[32][40];
    __shared__ u16 BsH[256][40];
    const int sbl = xcd_swz((int)blockIdx.x, (int)gridDim.x);
    const int b = sbl >> 2;
    const int m0 = (sbl & 3) * 32;
    const int t = threadIdx.x;
    const int lane = t & 63, wid = t >> 6;
    const int g = lane >> 4, r = lane & 15;

    f32x4 acc[16] = {};
    const int srow = t >> 2, scol = (t & 3) * 8;

    for (int k0 = 0; k0 < 256; k0 += 32) {
        size_t ga = (size_t)(b * 128 + m0 + srow) * 256 + k0 + scol;
        *(u32x4*)&AsH[srow][scol] = *(const u32x4*)(Mh + ga);
#pragma unroll
        for (int j = 0; j < 8; j++) {
            int idx = t + j * 128;
            int br = idx >> 2, bc = (idx & 3) * 8;
            size_t gb = (size_t)b * 65536 + (size_t)br * 256 + k0 + bc;
            *(u32x4*)&BsH[br][bc] = *(const u32x4*)(CtH + gb);
        }
        __syncthreads();

        f16x8 aF = *(const f16x8*)&AsH[16 * wid + r][g * 8];
#pragma unroll
        for (int ni = 0; ni < 16; ni++) {
            f16x8 bF = *(const f16x8*)&BsH[16 * ni + r][g * 8];
            acc[ni] = MFMA_F16(aF, bF, acc[ni]);
        }
        __syncthreads();
    }

#pragma unroll
    for (int rr = 0; rr < 4; rr++) {
        float mx = -3.0e38f;
#pragma unroll
        for (int ni = 0; ni < 16; ni++) mx = fmaxf(mx, acc[ni][rr]);
#pragma unroll
        for (int m = 1; m < 16; m <<= 1) mx = fmaxf(mx, __shfl_xor(mx, m));
        float s = 0.f;
#pragma unroll
        for (int ni = 0; ni < 16; ni++) {
            float e = __expf(acc[ni][rr] - mx);
            acc[ni][rr] = e;
            s += e;
        }
#pragma unroll
        for (int m = 1; m < 16; m <<= 1) s += __shfl_xor(s, m);
        float inv = 1.f / s;

        const int i_loc = m0 + 16 * wid + 4 * g + rr;          // 0..127
        const size_t arow = (size_t)(b * 128 + i_loc) * 256;
        const size_t obase = (size_t)b * 32768;                // 256*128
#pragma unroll
        for (int ni = 0; ni < 16; ni++) {
            float v = acc[ni][rr] * inv;
            int col = 16 * ni + r;
            attnH[arow + col] = f2h(v);                        // attn [i][l]
            out2[obase + (size_t)col * 128 + i_loc] = v;       // attn^T [l][i]
        }
    }
}

// ---------------------------------------------------------------------------
extern "C" void kernel_launch(void* const* d_in, const int* in_sizes, int n_in,
                              void* d_out, int out_size, void* d_ws, size_t ws_size,
                              hipStream_t stream) {
    const int B = 64, IDF = 128, CDF = 256, L = 256, S2 = 1024;
    const float* wc  = (const float*)d_in[0];   // [B, IDF, S2] = [8192][1024]
    const float* ctx = (const float*)d_in[1];   // [B, CDF, L]
    const float* W   = (const float*)d_in[2];   // [S2, CDF]
    float* out1 = (float*)d_out;                          // [B,IDF,S2]
    float* out2 = (float*)d_out + (size_t)B * IDF * S2;   // [B,L,IDF]

    char* ws = (char*)d_ws;
    size_t off = 0;
    auto alloc = [&](size_t bytes) -> char* {
        char* p = ws + off;
        off += (bytes + 255) & ~(size_t)255;
        return p;
    };
    u16* WtH   = (u16*)alloc((size_t)CDF * S2 * 2);        // W^T fp16 [256][1024]
    u16* ctxTH = (u16*)alloc((size_t)B * L * CDF * 2);     // ctx^T fp16 [B][l][c]
    u16* MH    = (u16*)alloc((size_t)B * IDF * CDF * 2);   // M fp16 [8192][256]
    u16* attnH = (u16*)alloc((size_t)B * IDF * L * 2);     // attn fp16 [8192][256]
    u16* YtH   = (u16*)alloc((size_t)B * IDF * CDF * 2);   // Yt fp16 [8192][256]
    (void)ws_size; // ~21.5 MB

    k_tcvt<<<dim3(CDF / 32, S2 / 32, 1), 256, 0, stream>>>(W, WtH, S2, CDF);
    k_tcvt<<<dim3(L / 32, CDF / 32, B), 256, 0, stream>>>(ctx, ctxTH, CDF, L);

    // G1: M = wc @ W  (A = wc f32 on-fly, BT = W^T fp16), out fp16
    k_gemm3<128, 64, 4, 2, true, false, 1><<<256, 256, 0, stream>>>(
        wc, nullptr, nullptr, WtH, MH, nullptr,
        4, 64, 256, 1024, 0, 0, 0);

    // G2: logits + softmax -> attn fp16 + out2 f32
    k_logits_softmax<<<256, 128, 0, stream>>>(MH, ctxTH, attnH, out2);

    // G3: Yt = attn @ ctx^T' (A = attn fp16, BT = ctx f32 on-fly), out fp16
    k_gemm3<64, 64, 2, 2, false, true, 1><<<512, 256, 0, stream>>>(
        nullptr, attnH, ctx, nullptr, YtH, nullptr,
        4, 2, 256, 256,
        (long long)IDF * L, (long long)CDF * L, (long long)IDF * CDF);

    // G4: out1 = Yt @ W^T' (A = Yt fp16, BT = W f32 on-fly), out f32
    k_gemm3<128, 128, 4, 4, false, true, 0><<<512, 256, 0, stream>>>(
        nullptr, YtH, W, nullptr, nullptr, out1,
        8, 64, 1024, 256,
        0, 0, 0);
}

// Round 5
// 60.264 us; speedup vs baseline: 1.6361x; 1.3357x over previous
//
#include <hip/hip_runtime.h>

// B=64, IDF=128, CDF=256, L=256, S2=1024.
// Full-fp16 pipeline (converts fused into GEMM staging, banded coalesced loads):
//   tcvtW : W   -> W^T fp16 [256][1024]
//   tcvtC : ctx -> ctx^T fp16 [B][L][C]
//   G1: M    = wc(f32->fp16 on-fly) @ W^T(fp16)   [8192x256]  64x64 tiles, 512 blocks
//   G2: logit= M(fp16) @ ctx^T(fp16) + softmax    -> attn fp16 + out2 f32, 512 blocks
//   G3: Yt   = attn(fp16) @ ctx(f32->fp16 on-fly) [128x256]/b 64x64, 512 blocks
//   G4: out1 = Yt(fp16) @ W(f32->fp16 on-fly)     [8192x1024] 128x64, 1024 blocks

typedef unsigned short u16;
typedef _Float16 f16;
typedef __attribute__((ext_vector_type(8))) _Float16 f16x8;    // 4 VGPRs
typedef __attribute__((ext_vector_type(4))) float f32x4;       // MFMA acc
typedef __attribute__((ext_vector_type(4))) unsigned int u32x4;

#define MFMA_F16(a, b, c) __builtin_amdgcn_mfma_f32_16x16x32_f16((a), (b), (c), 0, 0, 0)

__device__ __forceinline__ u16 f2h(float v) {
    f16 h = (f16)v;                      // v_cvt_f16_f32, RNE
    return __builtin_bit_cast(u16, h);
}
__device__ __forceinline__ unsigned pk2h(float a, float b) {
    return (unsigned)f2h(a) | ((unsigned)f2h(b) << 16);
}
// XCD-chunked bijective block swizzle (grid size divisible by 8)
__device__ __forceinline__ int xcd_swz(int bid, int nwg) {
    return (bid & 7) * (nwg >> 3) + (bid >> 3);
}

// ---------------------------------------------------------------------------
// Transpose-convert: src [nmat][R][C] f32 -> dstT [nmat][C][R] fp16.
__global__ void k_tcvt(const float* __restrict__ src, u16* __restrict__ dstT,
                       int R, int C) {
    __shared__ float tile[32][33];
    const int b = blockIdx.z;
    const float* s = src + (size_t)b * R * C;
    const int c0 = blockIdx.x * 32, r0 = blockIdx.y * 32;
    const int tx = threadIdx.x & 31, ty0 = threadIdx.x >> 5;   // 32 x 8
#pragma unroll
    for (int i = 0; i < 4; i++) {
        int ty = ty0 + i * 8;
        tile[ty][tx] = s[(size_t)(r0 + ty) * C + c0 + tx];
    }
    __syncthreads();
#pragma unroll
    for (int i = 0; i < 4; i++) {
        int ty = ty0 + i * 8;
        dstT[(size_t)b * R * C + (size_t)(c0 + ty) * R + r0 + tx] = f2h(tile[tx][ty]);
    }
}

// ---------------------------------------------------------------------------
// fp16 MFMA GEMM: D[m][n] = sum_k A[m][k] * BT[n][k].  BK=64, 4 waves (2x2),
// wave tile (FM*16)x(FN*16). Double-buffered swizzled LDS (group ^ (row&7)).
// Banded coalesced staging:
//   f32 src : lane -> (row = t>>4, float4 = t&15); PASSES = ROWS/16
//   fp16 src: lane -> (row = t>>3, 16Bgrp = t&7);  PASSES = ROWS/32
// EPI: 0 = f32 out, 1 = fp16 out.
template<int BM, int BN, int FM, int FN, bool AF32, bool BF32, int EPI>
__global__ __launch_bounds__(256, 2) void k_gemm5(
    const float* __restrict__ Af, const u16* __restrict__ Ah,
    const float* __restrict__ Bf, const u16* __restrict__ Bh,
    u16* __restrict__ outH, float* __restrict__ outF,
    int NBX, int NBY, int N, int K,
    long long sA, long long sB, long long sO)
{
    static_assert(2 * FM * 16 == BM && 2 * FN * 16 == BN, "2x2 waves");
    __shared__ __align__(16) u16 As[2][BM * 64];
    __shared__ __align__(16) u16 Bs[2][BN * 64];

    const int sbl = xcd_swz((int)blockIdx.x, (int)gridDim.x);
    const int bx = sbl % NBX;
    const int by = (sbl / NBX) % NBY;
    const int bz = sbl / (NBX * NBY);
    const int m0 = by * BM, n0 = bx * BN;

    const int t = threadIdx.x;
    const int lane = t & 63, wid = t >> 6;
    const int g = lane >> 4, r = lane & 15;
    const int mB = (wid >> 1) * FM * 16, nB = (wid & 1) * FN * 16;

    constexpr int PA = AF32 ? BM / 16 : BM / 32;   // staging passes
    constexpr int PB = BF32 ? BN / 16 : BN / 32;

    const float* Afp = nullptr; const u16* Ahp = nullptr;
    const float* Bfp = nullptr; const u16* Bhp = nullptr;
    if constexpr (AF32) Afp = Af + (size_t)bz * sA; else Ahp = Ah + (size_t)bz * sA;
    if constexpr (BF32) Bfp = Bf + (size_t)bz * sB; else Bhp = Bh + (size_t)bz * sB;

    float4 fa[AF32 ? PA : 1]; u32x4 ua[AF32 ? 1 : PA];
    float4 fb[BF32 ? PB : 1]; u32x4 ub[BF32 ? 1 : PB];

    auto LOAD = [&](int k0) {
        if constexpr (AF32) {
            const int row = t >> 4, f4 = t & 15;
#pragma unroll
            for (int i = 0; i < PA; i++)
                fa[i] = *((const float4*)(Afp + (size_t)(m0 + i * 16 + row) * K + k0) + f4);
        } else {
            const int row = t >> 3, grp = t & 7;
#pragma unroll
            for (int i = 0; i < PA; i++)
                ua[i] = *((const u32x4*)(Ahp + (size_t)(m0 + i * 32 + row) * K + k0) + grp);
        }
        if constexpr (BF32) {
            const int row = t >> 4, f4 = t & 15;
#pragma unroll
            for (int i = 0; i < PB; i++)
                fb[i] = *((const float4*)(Bfp + (size_t)(n0 + i * 16 + row) * K + k0) + f4);
        } else {
            const int row = t >> 3, grp = t & 7;
#pragma unroll
            for (int i = 0; i < PB; i++)
                ub[i] = *((const u32x4*)(Bhp + (size_t)(n0 + i * 32 + row) * K + k0) + grp);
        }
    };

    auto STORE = [&](int bi) {
        if constexpr (AF32) {
            const int row0 = t >> 4, grp = (t & 15) >> 1, half = t & 1;
#pragma unroll
            for (int i = 0; i < PA; i++) {
                const int row = i * 16 + row0;
                uint2 d = make_uint2(pk2h(fa[i].x, fa[i].y), pk2h(fa[i].z, fa[i].w));
                *(uint2*)&As[bi][row * 64 + ((grp ^ (row & 7)) << 3) + (half << 2)] = d;
            }
        } else {
            const int row0 = t >> 3, grp = t & 7;
#pragma unroll
            for (int i = 0; i < PA; i++) {
                const int row = i * 32 + row0;
                *(u32x4*)&As[bi][row * 64 + ((grp ^ (row & 7)) << 3)] = ua[i];
            }
        }
        if constexpr (BF32) {
            const int row0 = t >> 4, grp = (t & 15) >> 1, half = t & 1;
#pragma unroll
            for (int i = 0; i < PB; i++) {
                const int row = i * 16 + row0;
                uint2 d = make_uint2(pk2h(fb[i].x, fb[i].y), pk2h(fb[i].z, fb[i].w));
                *(uint2*)&Bs[bi][row * 64 + ((grp ^ (row & 7)) << 3) + (half << 2)] = d;
            }
        } else {
            const int row0 = t >> 3, grp = t & 7;
#pragma unroll
            for (int i = 0; i < PB; i++) {
                const int row = i * 32 + row0;
                *(u32x4*)&Bs[bi][row * 64 + ((grp ^ (row & 7)) << 3)] = ub[i];
            }
        }
    };

    f32x4 acc[FM][FN] = {};
    int cur = 0;
    LOAD(0);
    STORE(0);
    __syncthreads();

    const int nt = K >> 6;
    for (int tt = 0; tt < nt; ++tt) {
        if (tt + 1 < nt) LOAD((tt + 1) << 6);

#pragma unroll
        for (int kh = 0; kh < 2; kh++) {
            f16x8 aF[FM], bF[FN];
#pragma unroll
            for (int mi = 0; mi < FM; mi++) {
                const int row = mB + 16 * mi + r;
                const int slot = ((kh << 2) | g) ^ (row & 7);
                aF[mi] = *(const f16x8*)&As[cur][row * 64 + slot * 8];
            }
#pragma unroll
            for (int ni = 0; ni < FN; ni++) {
                const int row = nB + 16 * ni + r;
                const int slot = ((kh << 2) | g) ^ (row & 7);
                bF[ni] = *(const f16x8*)&Bs[cur][row * 64 + slot * 8];
            }
#pragma unroll
            for (int mi = 0; mi < FM; mi++)
#pragma unroll
                for (int ni = 0; ni < FN; ni++)
                    acc[mi][ni] = MFMA_F16(aF[mi], bF[ni], acc[mi][ni]);
        }

        if (tt + 1 < nt) STORE(cur ^ 1);
        __syncthreads();
        cur ^= 1;
    }

#pragma unroll
    for (int mi = 0; mi < FM; mi++)
#pragma unroll
        for (int ni = 0; ni < FN; ni++)
#pragma unroll
            for (int rr = 0; rr < 4; rr++) {
                const int row = m0 + mB + 16 * mi + 4 * g + rr;  // C/D: row=4*(lane>>4)+reg
                const int col = n0 + nB + 16 * ni + r;           //      col=lane&15
                const float v = acc[mi][ni][rr];
                const size_t o = (size_t)bz * sO + (size_t)row * N + col;
                if constexpr (EPI == 0) outF[o] = v;
                else outH[o] = f2h(v);
            }
}

// ---------------------------------------------------------------------------
// logits = M @ ctx (fp16 via ctxT) + softmax over L=256.
// 512 blocks x 256 thr; block = 16 rows x 256 cols, 4 waves split N (64 cols each).
// A (16x256) staged once; B (256 x 64k) single-buffer with reg prefetch.
__global__ __launch_bounds__(256, 2) void k_logits_softmax(
    const u16* __restrict__ Mh, const u16* __restrict__ CtH,
    u16* __restrict__ attnH, float* __restrict__ out2)
{
    __shared__ __align__(16) u16 As[16 * 256];    // 8 KB swizzled (32 grps/row)
    __shared__ __align__(16) u16 Bs[256 * 64];    // 32 KB swizzled (8 grps/row)
    __shared__ float red[16][4];

    const int sbl = xcd_swz((int)blockIdx.x, (int)gridDim.x);
    const int b  = sbl >> 3;
    const int m0 = (sbl & 7) * 16;
    const int t = threadIdx.x;
    const int lane = t & 63, w = t >> 6;
    const int g = lane >> 4, r = lane & 15;

    // stage A once: rows b*128+m0 .. +15, 256 k each
    {
        const u32x4* src = (const u32x4*)(Mh + (size_t)(b * 128 + m0) * 256);
#pragma unroll
        for (int i = 0; i < 2; i++) {
            const int row = i * 8 + (t >> 5), grp = t & 31;
            u32x4 v = src[row * 32 + grp];
            *(u32x4*)&As[row * 256 + ((grp ^ (row & 7)) << 3)] = v;
        }
    }
    const u16* Bsrc = CtH + (size_t)b * 65536;

    u32x4 ub[8];
    auto BLOAD = [&](int kc) {
        const int row = t >> 3, grp = t & 7;
#pragma unroll
        for (int i = 0; i < 8; i++)
            ub[i] = *((const u32x4*)(Bsrc + (size_t)(i * 32 + row) * 256 + kc * 64) + grp);
    };
    auto BSTORE = [&]() {
        const int row0 = t >> 3, grp = t & 7;
#pragma unroll
        for (int i = 0; i < 8; i++) {
            const int row = i * 32 + row0;
            *(u32x4*)&Bs[row * 64 + ((grp ^ (row & 7)) << 3)] = ub[i];
        }
    };

    f32x4 acc[4] = {};
    BLOAD(0);
#pragma unroll
    for (int kc = 0; kc < 4; kc++) {
        BSTORE();
        __syncthreads();
        if (kc < 3) BLOAD(kc + 1);
#pragma unroll
        for (int kh = 0; kh < 2; kh++) {
            const int kq = kc * 2 + kh;
            const int aslot = (kq * 4 + g) ^ (r & 7);
            f16x8 aF = *(const f16x8*)&As[r * 256 + aslot * 8];
#pragma unroll
            for (int ni = 0; ni < 4; ni++) {
                const int row = w * 64 + ni * 16 + r;
                const int bslot = ((kh << 2) | g) ^ (row & 7);
                f16x8 bF = *(const f16x8*)&Bs[row * 64 + bslot * 8];
                acc[ni] = MFMA_F16(aF, bF, acc[ni]);
            }
        }
        __syncthreads();
    }

    // ---- softmax over 256 cols; lane holds rows 4g+rr (rr=0..3), cols w*64+16ni+r
    float mx4[4], s4[4], gmx[4];
#pragma unroll
    for (int rr = 0; rr < 4; rr++) {
        float mx = fmaxf(fmaxf(acc[0][rr], acc[1][rr]), fmaxf(acc[2][rr], acc[3][rr]));
#pragma unroll
        for (int m = 1; m < 16; m <<= 1) mx = fmaxf(mx, __shfl_xor(mx, m));
        mx4[rr] = mx;
    }
    if (r == 0) {
#pragma unroll
        for (int rr = 0; rr < 4; rr++) red[4 * g + rr][w] = mx4[rr];
    }
    __syncthreads();
#pragma unroll
    for (int rr = 0; rr < 4; rr++) {
        const int lrow = 4 * g + rr;
        gmx[rr] = fmaxf(fmaxf(red[lrow][0], red[lrow][1]),
                        fmaxf(red[lrow][2], red[lrow][3]));
        float s = 0.f;
#pragma unroll
        for (int ni = 0; ni < 4; ni++) {
            float e = __expf(acc[ni][rr] - gmx[rr]);
            acc[ni][rr] = e;
            s += e;
        }
#pragma unroll
        for (int m = 1; m < 16; m <<= 1) s += __shfl_xor(s, m);
        s4[rr] = s;
    }
    __syncthreads();                   // red reuse
    if (r == 0) {
#pragma unroll
        for (int rr = 0; rr < 4; rr++) red[4 * g + rr][w] = s4[rr];
    }
    __syncthreads();
#pragma unroll
    for (int rr = 0; rr < 4; rr++) {
        const int lrow = 4 * g + rr;
        const float inv = 1.f / (red[lrow][0] + red[lrow][1] +
                                 red[lrow][2] + red[lrow][3]);
        const int grow = b * 128 + m0 + lrow;
#pragma unroll
        for (int ni = 0; ni < 4; ni++) {
            const float v = acc[ni][rr] * inv;
            const int col = w * 64 + ni * 16 + r;
            attnH[(size_t)grow * 256 + col] = f2h(v);                  // attn [i][l]
            out2[(size_t)b * 32768 + (size_t)col * 128 + m0 + lrow] = v; // attn^T [l][i]
        }
    }
}

// ---------------------------------------------------------------------------
extern "C" void kernel_launch(void* const* d_in, const int* in_sizes, int n_in,
                              void* d_out, int out_size, void* d_ws, size_t ws_size,
                              hipStream_t stream) {
    const int B = 64, IDF = 128, CDF = 256, L = 256, S2 = 1024;
    const float* wc  = (const float*)d_in[0];   // [B, IDF, S2] = [8192][1024]
    const float* ctx = (const float*)d_in[1];   // [B, CDF, L]
    const float* W   = (const float*)d_in[2];   // [S2, CDF]
    float* out1 = (float*)d_out;                          // [B,IDF,S2]
    float* out2 = (float*)d_out + (size_t)B * IDF * S2;   // [B,L,IDF]

    char* ws = (char*)d_ws;
    size_t off = 0;
    auto alloc = [&](size_t bytes) -> char* {
        char* p = ws + off;
        off += (bytes + 255) & ~(size_t)255;
        return p;
    };
    u16* WtH   = (u16*)alloc((size_t)CDF * S2 * 2);        // W^T fp16 [256][1024]
    u16* ctxTH = (u16*)alloc((size_t)B * L * CDF * 2);     // ctx^T fp16 [B][l][c]
    u16* MH    = (u16*)alloc((size_t)B * IDF * CDF * 2);   // M fp16 [8192][256]
    u16* attnH = (u16*)alloc((size_t)B * IDF * L * 2);     // attn fp16 [8192][256]
    u16* YtH   = (u16*)alloc((size_t)B * IDF * CDF * 2);   // Yt fp16 [8192][256]
    (void)ws_size; // ~21.5 MB

    k_tcvt<<<dim3(CDF / 32, S2 / 32, 1), 256, 0, stream>>>(W, WtH, S2, CDF);
    k_tcvt<<<dim3(L / 32, CDF / 32, B), 256, 0, stream>>>(ctx, ctxTH, CDF, L);

    // G1: M = wc @ W  (A = wc f32 on-fly, BT = W^T fp16), 64x64, 512 blocks
    k_gemm5<64, 64, 2, 2, true, false, 1><<<512, 256, 0, stream>>>(
        wc, nullptr, nullptr, WtH, MH, nullptr,
        4, 128, 256, 1024, 0, 0, 0);

    // G2: logits + softmax -> attn fp16 + out2 f32, 512 blocks
    k_logits_softmax<<<512, 256, 0, stream>>>(MH, ctxTH, attnH, out2);

    // G3: Yt = attn @ ctx^T' (A = attn fp16, BT = ctx f32 on-fly), 64x64, 512 blocks
    k_gemm5<64, 64, 2, 2, false, true, 1><<<512, 256, 0, stream>>>(
        nullptr, attnH, ctx, nullptr, YtH, nullptr,
        4, 2, 256, 256,
        (long long)IDF * L, (long long)CDF * L, (long long)IDF * CDF);

    // G4: out1 = Yt @ W^T' (A = Yt fp16, BT = W f32 on-fly), 128x64, 1024 blocks
    k_gemm5<128, 64, 4, 2, false, true, 0><<<1024, 256, 0, stream>>>(
        nullptr, YtH, W, nullptr, nullptr, out1,
        16, 64, 1024, 256, 0, 0, 0);
}

// Round 6
// 59.233 us; speedup vs baseline: 1.6646x; 1.0174x over previous
//
#include <hip/hip_runtime.h>

// B=64, IDF=128, CDF=256, L=256, S2=1024.
// Full-fp16 pipeline, 4 kernels:
//   tcvt_all : W -> W^T fp16 ; ctx -> ctx^T fp16 + ctx plain fp16
//   G1 : M = wc(f32->fp16 on-fly) @ W^T(fp16)       [8192x256]   (k_gemm5)
//   FUSED: logits = M @ ctx^T, softmax, out2 = P^T (coalesced via LDS),
//          Yt = P @ ctx^T' (PV)                      [16x256]/blk
//   G4 : out1 = Yt(fp16) @ W(f32->fp16 on-fly)      [8192x1024]  (k_gemm5)

typedef unsigned short u16;
typedef _Float16 f16;
typedef __attribute__((ext_vector_type(8))) _Float16 f16x8;    // 4 VGPRs
typedef __attribute__((ext_vector_type(4))) float f32x4;       // MFMA acc
typedef __attribute__((ext_vector_type(4))) unsigned int u32x4;

#define MFMA_F16(a, b, c) __builtin_amdgcn_mfma_f32_16x16x32_f16((a), (b), (c), 0, 0, 0)

__device__ __forceinline__ u16 f2h(float v) {
    f16 h = (f16)v;                      // v_cvt_f16_f32, RNE
    return __builtin_bit_cast(u16, h);
}
__device__ __forceinline__ float h2f(u16 h) {
    return (float)__builtin_bit_cast(f16, h);
}
__device__ __forceinline__ unsigned pk2h(float a, float b) {
    return (unsigned)f2h(a) | ((unsigned)f2h(b) << 16);
}
// XCD-chunked bijective block swizzle (grid size divisible by 8)
__device__ __forceinline__ int xcd_swz(int bid, int nwg) {
    return (bid & 7) * (nwg >> 3) + (bid >> 3);
}

// ---------------------------------------------------------------------------
// One launch: z<64 -> ctx mat z: write CtP (plain fp16) + CtH (transposed fp16);
//             z>=64 -> W row-band: write WtH (transposed fp16).
// grid (8, 8, 68), block 256.
__global__ void k_tcvt_all(const float* __restrict__ Wsrc,
                           const float* __restrict__ ctx,
                           u16* __restrict__ WtH, u16* __restrict__ CtH,
                           u16* __restrict__ CtP) {
    __shared__ float tile[32][33];
    const int z = blockIdx.z;
    const int tx = threadIdx.x & 31, ty0 = threadIdx.x >> 5;   // 32 x 8
    if (z < 64) {
        const float* s = ctx + (size_t)z * 65536;
        const int c0 = blockIdx.x * 32, r0 = blockIdx.y * 32;
#pragma unroll
        for (int i = 0; i < 4; i++) {
            int ty = ty0 + i * 8;
            float v = s[(size_t)(r0 + ty) * 256 + c0 + tx];
            tile[ty][tx] = v;
            CtP[(size_t)z * 65536 + (size_t)(r0 + ty) * 256 + c0 + tx] = f2h(v);
        }
        __syncthreads();
#pragma unroll
        for (int i = 0; i < 4; i++) {
            int ty = ty0 + i * 8;
            CtH[(size_t)z * 65536 + (size_t)(c0 + ty) * 256 + r0 + tx] = f2h(tile[tx][ty]);
        }
    } else {
        const int r0 = (z - 64) * 256 + blockIdx.y * 32;       // W rows
        const int c0 = blockIdx.x * 32;
#pragma unroll
        for (int i = 0; i < 4; i++) {
            int ty = ty0 + i * 8;
            tile[ty][tx] = Wsrc[(size_t)(r0 + ty) * 256 + c0 + tx];
        }
        __syncthreads();
#pragma unroll
        for (int i = 0; i < 4; i++) {
            int ty = ty0 + i * 8;
            WtH[(size_t)(c0 + ty) * 1024 + r0 + tx] = f2h(tile[tx][ty]);
        }
    }
}

// ---------------------------------------------------------------------------
// fp16 MFMA GEMM: D[m][n] = sum_k A[m][k] * BT[n][k].  BK=64, 4 waves (2x2),
// wave tile (FM*16)x(FN*16). Double-buffered swizzled LDS (group ^ (row&7)).
// Banded coalesced staging. EPI: 0 = f32 out, 1 = fp16 out.
template<int BM, int BN, int FM, int FN, bool AF32, bool BF32, int EPI>
__global__ __launch_bounds__(256, 2) void k_gemm5(
    const float* __restrict__ Af, const u16* __restrict__ Ah,
    const float* __restrict__ Bf, const u16* __restrict__ Bh,
    u16* __restrict__ outH, float* __restrict__ outF,
    int NBX, int NBY, int N, int K,
    long long sA, long long sB, long long sO)
{
    static_assert(2 * FM * 16 == BM && 2 * FN * 16 == BN, "2x2 waves");
    __shared__ __align__(16) u16 As[2][BM * 64];
    __shared__ __align__(16) u16 Bs[2][BN * 64];

    const int sbl = xcd_swz((int)blockIdx.x, (int)gridDim.x);
    const int bx = sbl % NBX;
    const int by = (sbl / NBX) % NBY;
    const int bz = sbl / (NBX * NBY);
    const int m0 = by * BM, n0 = bx * BN;

    const int t = threadIdx.x;
    const int lane = t & 63, wid = t >> 6;
    const int g = lane >> 4, r = lane & 15;
    const int mB = (wid >> 1) * FM * 16, nB = (wid & 1) * FN * 16;

    constexpr int PA = AF32 ? BM / 16 : BM / 32;   // staging passes
    constexpr int PB = BF32 ? BN / 16 : BN / 32;

    const float* Afp = nullptr; const u16* Ahp = nullptr;
    const float* Bfp = nullptr; const u16* Bhp = nullptr;
    if constexpr (AF32) Afp = Af + (size_t)bz * sA; else Ahp = Ah + (size_t)bz * sA;
    if constexpr (BF32) Bfp = Bf + (size_t)bz * sB; else Bhp = Bh + (size_t)bz * sB;

    float4 fa[AF32 ? PA : 1]; u32x4 ua[AF32 ? 1 : PA];
    float4 fb[BF32 ? PB : 1]; u32x4 ub[BF32 ? 1 : PB];

    auto LOAD = [&](int k0) {
        if constexpr (AF32) {
            const int row = t >> 4, f4 = t & 15;
#pragma unroll
            for (int i = 0; i < PA; i++)
                fa[i] = *((const float4*)(Afp + (size_t)(m0 + i * 16 + row) * K + k0) + f4);
        } else {
            const int row = t >> 3, grp = t & 7;
#pragma unroll
            for (int i = 0; i < PA; i++)
                ua[i] = *((const u32x4*)(Ahp + (size_t)(m0 + i * 32 + row) * K + k0) + grp);
        }
        if constexpr (BF32) {
            const int row = t >> 4, f4 = t & 15;
#pragma unroll
            for (int i = 0; i < PB; i++)
                fb[i] = *((const float4*)(Bfp + (size_t)(n0 + i * 16 + row) * K + k0) + f4);
        } else {
            const int row = t >> 3, grp = t & 7;
#pragma unroll
            for (int i = 0; i < PB; i++)
                ub[i] = *((const u32x4*)(Bhp + (size_t)(n0 + i * 32 + row) * K + k0) + grp);
        }
    };

    auto STORE = [&](int bi) {
        if constexpr (AF32) {
            const int row0 = t >> 4, grp = (t & 15) >> 1, half = t & 1;
#pragma unroll
            for (int i = 0; i < PA; i++) {
                const int row = i * 16 + row0;
                uint2 d = make_uint2(pk2h(fa[i].x, fa[i].y), pk2h(fa[i].z, fa[i].w));
                *(uint2*)&As[bi][row * 64 + ((grp ^ (row & 7)) << 3) + (half << 2)] = d;
            }
        } else {
            const int row0 = t >> 3, grp = t & 7;
#pragma unroll
            for (int i = 0; i < PA; i++) {
                const int row = i * 32 + row0;
                *(u32x4*)&As[bi][row * 64 + ((grp ^ (row & 7)) << 3)] = ua[i];
            }
        }
        if constexpr (BF32) {
            const int row0 = t >> 4, grp = (t & 15) >> 1, half = t & 1;
#pragma unroll
            for (int i = 0; i < PB; i++) {
                const int row = i * 16 + row0;
                uint2 d = make_uint2(pk2h(fb[i].x, fb[i].y), pk2h(fb[i].z, fb[i].w));
                *(uint2*)&Bs[bi][row * 64 + ((grp ^ (row & 7)) << 3) + (half << 2)] = d;
            }
        } else {
            const int row0 = t >> 3, grp = t & 7;
#pragma unroll
            for (int i = 0; i < PB; i++) {
                const int row = i * 32 + row0;
                *(u32x4*)&Bs[bi][row * 64 + ((grp ^ (row & 7)) << 3)] = ub[i];
            }
        }
    };

    f32x4 acc[FM][FN] = {};
    int cur = 0;
    LOAD(0);
    STORE(0);
    __syncthreads();

    const int nt = K >> 6;
    for (int tt = 0; tt < nt; ++tt) {
        if (tt + 1 < nt) LOAD((tt + 1) << 6);

#pragma unroll
        for (int kh = 0; kh < 2; kh++) {
            f16x8 aF[FM], bF[FN];
#pragma unroll
            for (int mi = 0; mi < FM; mi++) {
                const int row = mB + 16 * mi + r;
                const int slot = ((kh << 2) | g) ^ (row & 7);
                aF[mi] = *(const f16x8*)&As[cur][row * 64 + slot * 8];
            }
#pragma unroll
            for (int ni = 0; ni < FN; ni++) {
                const int row = nB + 16 * ni + r;
                const int slot = ((kh << 2) | g) ^ (row & 7);
                bF[ni] = *(const f16x8*)&Bs[cur][row * 64 + slot * 8];
            }
#pragma unroll
            for (int mi = 0; mi < FM; mi++)
#pragma unroll
                for (int ni = 0; ni < FN; ni++)
                    acc[mi][ni] = MFMA_F16(aF[mi], bF[ni], acc[mi][ni]);
        }

        if (tt + 1 < nt) STORE(cur ^ 1);
        __syncthreads();
        cur ^= 1;
    }

#pragma unroll
    for (int mi = 0; mi < FM; mi++)
#pragma unroll
        for (int ni = 0; ni < FN; ni++)
#pragma unroll
            for (int rr = 0; rr < 4; rr++) {
                const int row = m0 + mB + 16 * mi + 4 * g + rr;  // C/D: row=4*(lane>>4)+reg
                const int col = n0 + nB + 16 * ni + r;           //      col=lane&15
                const float v = acc[mi][ni][rr];
                const size_t o = (size_t)bz * sO + (size_t)row * N + col;
                if constexpr (EPI == 0) outF[o] = v;
                else outH[o] = f2h(v);
            }
}

// ---------------------------------------------------------------------------
// FUSED: logits = M @ ctx (via ctxT fp16) -> softmax -> P ->
//        out2 = P^T (coalesced through LDS) and Yt = P @ ctx^T' (PV, via ctxP).
// 512 blocks x 256 thr; block = 16 rows of one batch, 4 waves split N=256.
// LDS: smA 8 KB (logits-A, then P fp16), smB 32 KB (ctxT chunks, then ctxP chunks).
__global__ __launch_bounds__(256, 2) void k_fused(
    const u16* __restrict__ Mh, const u16* __restrict__ CtH,
    const u16* __restrict__ CtP, u16* __restrict__ YtH,
    float* __restrict__ out2)
{
    __shared__ __align__(16) u16 smA[16 * 256];
    __shared__ __align__(16) u16 smB[256 * 64];
    __shared__ float red[16][4];

    const int sbl = xcd_swz((int)blockIdx.x, (int)gridDim.x);
    const int b  = sbl >> 3;
    const int m0 = (sbl & 7) * 16;
    const int t = threadIdx.x;
    const int lane = t & 63, w = t >> 6;
    const int g = lane >> 4, r = lane & 15;

    // stage A once (16 rows of Mh), 32 groups/row, slot = grp ^ (row&7)
    {
        const u32x4* src = (const u32x4*)(Mh + (size_t)(b * 128 + m0) * 256);
#pragma unroll
        for (int i = 0; i < 2; i++) {
            const int row = i * 8 + (t >> 5), grp = t & 31;
            u32x4 v = src[row * 32 + grp];
            *(u32x4*)&smA[row * 256 + ((grp ^ (row & 7)) << 3)] = v;
        }
    }
    const u16* Bsrc = CtH + (size_t)b * 65536;   // ctx^T [l][c]
    const u16* Psrc = CtP + (size_t)b * 65536;   // ctx   [c][l]

    u32x4 ub[8];
    auto BLOAD = [&](const u16* base, int kc) {
        const int row = t >> 3, grp = t & 7;
#pragma unroll
        for (int i = 0; i < 8; i++)
            ub[i] = *((const u32x4*)(base + (size_t)(i * 32 + row) * 256 + kc * 64) + grp);
    };
    auto BSTORE = [&]() {
        const int row0 = t >> 3, grp = t & 7;
#pragma unroll
        for (int i = 0; i < 8; i++) {
            const int row = i * 32 + row0;
            *(u32x4*)&smB[row * 64 + ((grp ^ (row & 7)) << 3)] = ub[i];
        }
    };

    // ---- logits: acc[ni][rr] = logit[4g+rr][w*64+16ni+r]
    f32x4 acc[4] = {};
    BLOAD(Bsrc, 0);
#pragma unroll
    for (int kc = 0; kc < 4; kc++) {
        BSTORE();
        __syncthreads();
        if (kc < 3) BLOAD(Bsrc, kc + 1);
#pragma unroll
        for (int kh = 0; kh < 2; kh++) {
            const int kq = kc * 2 + kh;
            const int aslot = (kq * 4 + g) ^ (r & 7);
            f16x8 aF = *(const f16x8*)&smA[r * 256 + aslot * 8];
#pragma unroll
            for (int ni = 0; ni < 4; ni++) {
                const int row = w * 64 + ni * 16 + r;
                const int bslot = ((kh << 2) | g) ^ (row & 7);
                f16x8 bF = *(const f16x8*)&smB[row * 64 + bslot * 8];
                acc[ni] = MFMA_F16(aF, bF, acc[ni]);
            }
        }
        __syncthreads();
    }

    // prefetch first PV chunk while softmax runs
    BLOAD(Psrc, 0);

    // ---- softmax over 256 cols (4 waves share each row via red[])
    float mx4[4], s4[4];
#pragma unroll
    for (int rr = 0; rr < 4; rr++) {
        float mx = fmaxf(fmaxf(acc[0][rr], acc[1][rr]), fmaxf(acc[2][rr], acc[3][rr]));
#pragma unroll
        for (int m = 1; m < 16; m <<= 1) mx = fmaxf(mx, __shfl_xor(mx, m));
        mx4[rr] = mx;
    }
    if (r == 0) {
#pragma unroll
        for (int rr = 0; rr < 4; rr++) red[4 * g + rr][w] = mx4[rr];
    }
    __syncthreads();
#pragma unroll
    for (int rr = 0; rr < 4; rr++) {
        const int lrow = 4 * g + rr;
        const float gmx = fmaxf(fmaxf(red[lrow][0], red[lrow][1]),
                                fmaxf(red[lrow][2], red[lrow][3]));
        float s = 0.f;
#pragma unroll
        for (int ni = 0; ni < 4; ni++) {
            float e = __expf(acc[ni][rr] - gmx);
            acc[ni][rr] = e;
            s += e;
        }
#pragma unroll
        for (int m = 1; m < 16; m <<= 1) s += __shfl_xor(s, m);
        s4[rr] = s;
    }
    __syncthreads();
    if (r == 0) {
#pragma unroll
        for (int rr = 0; rr < 4; rr++) red[4 * g + rr][w] = s4[rr];
    }
    __syncthreads();

    // ---- normalize, park P (fp16, swizzled) into smA (logits-A is dead)
#pragma unroll
    for (int rr = 0; rr < 4; rr++) {
        const int lrow = 4 * g + rr;
        const float inv = 1.f / (red[lrow][0] + red[lrow][1] +
                                 red[lrow][2] + red[lrow][3]);
#pragma unroll
        for (int ni = 0; ni < 4; ni++) {
            const float v = acc[ni][rr] * inv;
            const int col = w * 64 + ni * 16 + r;
            smA[lrow * 256 + (((col >> 3) ^ (lrow & 7)) << 3) + (col & 7)] = f2h(v);
        }
    }
    __syncthreads();

    // ---- out2 = P^T, coalesced: thread t owns column l = t, writes 64 B run
    {
        const int l = t;
        float vals[16];
#pragma unroll
        for (int row = 0; row < 16; row++)
            vals[row] = h2f(smA[row * 256 + (((l >> 3) ^ (row & 7)) << 3) + (l & 7)]);
        float4* dst = (float4*)(out2 + (size_t)b * 32768 + (size_t)l * 128 + m0);
#pragma unroll
        for (int q = 0; q < 4; q++)
            dst[q] = make_float4(vals[4 * q], vals[4 * q + 1],
                                 vals[4 * q + 2], vals[4 * q + 3]);
    }

    // ---- PV: Yt[i][c] = sum_l P[i][l] * ctx[c][l]  (BT rows = ctxP rows)
    f32x4 acc2[4] = {};
#pragma unroll
    for (int kc = 0; kc < 4; kc++) {
        BSTORE();
        __syncthreads();
        if (kc < 3) BLOAD(Psrc, kc + 1);
#pragma unroll
        for (int kh = 0; kh < 2; kh++) {
            const int kq = kc * 2 + kh;
            const int aslot = (kq * 4 + g) ^ (r & 7);
            f16x8 aF = *(const f16x8*)&smA[r * 256 + aslot * 8];
#pragma unroll
            for (int ni = 0; ni < 4; ni++) {
                const int row = w * 64 + ni * 16 + r;
                const int bslot = ((kh << 2) | g) ^ (row & 7);
                f16x8 bF = *(const f16x8*)&smB[row * 64 + bslot * 8];
                acc2[ni] = MFMA_F16(aF, bF, acc2[ni]);
            }
        }
        __syncthreads();
    }

    // ---- Yt epilogue (fp16)
    u16* Yb = YtH + (size_t)b * 32768;           // [128][256] per batch
#pragma unroll
    for (int rr = 0; rr < 4; rr++) {
        const int row = m0 + 4 * g + rr;
#pragma unroll
        for (int ni = 0; ni < 4; ni++) {
            const int col = w * 64 + ni * 16 + r;
            Yb[(size_t)row * 256 + col] = f2h(acc2[ni][rr]);
        }
    }
}

// ---------------------------------------------------------------------------
extern "C" void kernel_launch(void* const* d_in, const int* in_sizes, int n_in,
                              void* d_out, int out_size, void* d_ws, size_t ws_size,
                              hipStream_t stream) {
    const int B = 64, IDF = 128, CDF = 256, L = 256, S2 = 1024;
    const float* wc  = (const float*)d_in[0];   // [B, IDF, S2] = [8192][1024]
    const float* ctx = (const float*)d_in[1];   // [B, CDF, L]
    const float* W   = (const float*)d_in[2];   // [S2, CDF]
    float* out1 = (float*)d_out;                          // [B,IDF,S2]
    float* out2 = (float*)d_out + (size_t)B * IDF * S2;   // [B,L,IDF]

    char* ws = (char*)d_ws;
    size_t off = 0;
    auto alloc = [&](size_t bytes) -> char* {
        char* p = ws + off;
        off += (bytes + 255) & ~(size_t)255;
        return p;
    };
    u16* WtH   = (u16*)alloc((size_t)CDF * S2 * 2);        // W^T fp16 [256][1024]
    u16* CtH   = (u16*)alloc((size_t)B * L * CDF * 2);     // ctx^T fp16 [B][l][c]
    u16* CtP   = (u16*)alloc((size_t)B * CDF * L * 2);     // ctx fp16  [B][c][l]
    u16* MH    = (u16*)alloc((size_t)B * IDF * CDF * 2);   // M fp16 [8192][256]
    u16* YtH   = (u16*)alloc((size_t)B * IDF * CDF * 2);   // Yt fp16 [8192][256]
    (void)ws_size; // ~26 MB

    // converts (one launch): ctx -> CtH + CtP ; W -> WtH
    k_tcvt_all<<<dim3(8, 8, 68), 256, 0, stream>>>(W, ctx, WtH, CtH, CtP);

    // G1: M = wc @ W  (A = wc f32 on-fly, BT = W^T fp16), 64x64, 512 blocks
    k_gemm5<64, 64, 2, 2, true, false, 1><<<512, 256, 0, stream>>>(
        wc, nullptr, nullptr, WtH, MH, nullptr,
        4, 128, 256, 1024, 0, 0, 0);

    // FUSED: logits + softmax + out2 + PV -> YtH, 512 blocks
    k_fused<<<512, 256, 0, stream>>>(MH, CtH, CtP, YtH, out2);

    // G4: out1 = Yt @ W^T' (A = Yt fp16, BT = W f32 on-fly), 128x64, 1024 blocks
    k_gemm5<128, 64, 4, 2, false, true, 0><<<1024, 256, 0, stream>>>(
        nullptr, YtH, W, nullptr, nullptr, out1,
        16, 64, 1024, 256, 0, 0, 0);
}